// Round 1
// baseline (179.419 us; speedup 1.0000x reference)
//
#include <hip/hip_runtime.h>

// TrajectoryScore: truncated-exponential mixture scoring + segment sums.
// 64 segments x 100,000 obs. Memory-bound stream: 153.6 MB read -> ~24 us floor.
//
// v2: fully-coalesced loads (lane i -> f4[base+i], 8 lines/wave-load instead of
// 24 with the old 3-f4-per-thread layout) + in-register obs reconstruction via
// one __shfl_down. Wave-chunk = 63 float4 = 84 whole obs (63 % 3 == 0 keeps the
// lane->component phase static: lane 3g owns obs 4g & 4g+1, lane 3g+1 owns
// 4g+2, lane 3g+2 owns 4g+3; straddling components come from lane L+1's "head"
// partial). Unroll x4 for MLP (8 float4 in flight / thread).

constexpr int ELT_BATCH       = 64;
constexpr int OBS_PER_ELT     = 100000;
constexpr int F4_PER_SEG      = OBS_PER_ELT * 3 / 4;   // 75000 float4 per segment per array
constexpr int CHUNK_F4        = 63;                    // 63 f4 = 252 floats = 84 obs per wave-chunk
constexpr int CHUNKS_PER_SEG  = (F4_PER_SEG + CHUNK_F4 - 1) / CHUNK_F4;  // 1191 (1190 full + 30-f4/40-obs tail)
constexpr int BLOCKS_PER_SEG  = 32;
constexpr int BLOCK           = 256;
constexpr int WAVES_PER_BLOCK = BLOCK / 64;
constexpr int WAVES_PER_SEG   = BLOCKS_PER_SEG * WAVES_PER_BLOCK;  // 128
constexpr int UNROLL          = 4;

__device__ __forceinline__ float wave_reduce_sum(float v) {
    #pragma unroll
    for (int off = 32; off > 0; off >>= 1)
        v += __shfl_down(v, off, 64);
    return v;
}

__global__ __launch_bounds__(BLOCK, 8) void TrajectoryScore_58145267253396_kernel(
    const float4* __restrict__ pred4,
    const float4* __restrict__ obs4,
    const float*  __restrict__ h_arr,
    const float*  __restrict__ lam_arr,
    const float*  __restrict__ th_arr,
    float*        __restrict__ out)
{
    const int seg        = blockIdx.x / BLOCKS_PER_SEG;
    const int blk_in_seg = blockIdx.x % BLOCKS_PER_SEG;
    const int tid  = threadIdx.x;
    const int lane = tid & 63;
    const int wave = tid >> 6;
    const int wseg = blk_in_seg * WAVES_PER_BLOCK + wave;   // 0..127 within segment

    // Wave-uniform per-segment params (broadcast scalar loads).
    const float h      = h_arr[seg];
    const float lam    = lam_arr[seg];
    const float th     = th_arr[seg];
    const float inv_th = 1.0f / th;
    const float coef   = h * lam / (1.0f - __expf(-lam));  // h * lam / (1 - e^-lam)
    const float omh    = 1.0f - h;
    const float nli    = -lam * inv_th;                    // exp(nli * s2) = exp(-lam * v)

    // Lane class within the 3-lane / 4-obs microgroup.
    const int  m  = lane % 3;
    const bool m0 = (m == 0);
    const bool m1 = (m == 1);

    const int seg_f4 = seg * F4_PER_SEG;

    float ll = 0.0f;   // sum of log(p) over close obs
    float hs = 0.0f;   // sum of p_hit_post over close & real-hit obs

    for (int c0 = wseg; c0 < CHUNKS_PER_SEG; c0 += UNROLL * WAVES_PER_SEG) {
        float4 A[UNROLL], B[UNROLL];
        int    act[UNROLL];

        // Issue all loads first: 8 canonical 16B/lane wave-loads in flight.
        #pragma unroll
        for (int u = 0; u < UNROLL; ++u) {
            const int c = c0 + u * WAVES_PER_SEG;      // wave-uniform
            if (c < CHUNKS_PER_SEG) {
                const int base = c * CHUNK_F4;
                const int idx  = seg_f4 + min(base + lane, F4_PER_SEG - 1);  // clamp: tail-safe
                A[u]   = pred4[idx];
                B[u]   = obs4[idx];
                act[u] = min(CHUNK_F4, F4_PER_SEG - base);  // 63, or 30 for the tail chunk
            } else {
                act[u] = 0;
            }
        }

        #pragma unroll
        for (int u = 0; u < UNROLL; ++u) {
            if (act[u] != 0) {                         // wave-uniform branch
                const float4 a = A[u], b = B[u];
                const float d0 = a.x - b.x, d1 = a.y - b.y, d2 = a.z - b.z, d3 = a.w - b.w;
                const float q0 = d0 * d0, q1 = d1 * d1, q2 = d2 * d2, q3 = d3 * d3;

                // "head" = this lane's leading components that belong to the obs
                // spilling over from lane L-1; consumed by lane L-1 via shfl_down.
                //   m==1 lane: q0+q1 (2 components),  m==2 lane: q0 (1 component).
                const float head = m1 ? (q0 + q1) : q0;
                const float hn   = __shfl_down(head, 1, 64);

                // obs A per lane:  m0 -> obs 4g   = q0+q1+q2            (local)
                //                  m1 -> obs 4g+2 = q2+q3 + head(L+1)
                //                  m2 -> obs 4g+3 = q1+q2+q3            (local)
                // obs B (m0 only): obs 4g+1 = q3 + head(L+1)
                const float t12 = q1 + q2;
                const float s2A = m0 ? (q0 + t12) : (m1 ? (q2 + q3 + hn) : (t12 + q3));
                const float s2B = q3 + hn;

                const bool lv = lane < act[u];         // lane validity (tail + lane 63)
                {
                    const float e  = __expf(nli * s2A);
                    const float ph = coef * e;
                    const float p  = ph + omh;
                    const float lp = __logf(p);
                    const float po = ph / p;
                    const bool  cl = (s2A < th) && lv;
                    ll += cl ? lp : 0.0f;
                    hs += (cl && po > 0.95f) ? po : 0.0f;
                }
                {
                    const float e  = __expf(nli * s2B);
                    const float ph = coef * e;
                    const float p  = ph + omh;
                    const float lp = __logf(p);
                    const float po = ph / p;
                    const bool  cl = (s2B < th) && lv && m0;
                    ll += cl ? lp : 0.0f;
                    hs += (cl && po > 0.95f) ? po : 0.0f;
                }
            }
        }
    }

    // Block reduction: 64-lane shuffle, then LDS across the 4 waves.
    ll = wave_reduce_sum(ll);
    hs = wave_reduce_sum(hs);

    __shared__ float sll[WAVES_PER_BLOCK];
    __shared__ float shs[WAVES_PER_BLOCK];
    if (lane == 0) { sll[wave] = ll; shs[wave] = hs; }
    __syncthreads();
    if (tid == 0) {
        float L = 0.0f, H = 0.0f;
        #pragma unroll
        for (int w = 0; w < WAVES_PER_BLOCK; ++w) { L += sll[w]; H += shs[w]; }
        atomicAdd(&out[seg], L);
        atomicAdd(&out[ELT_BATCH + seg], H);
        atomicAdd(&out[2 * ELT_BATCH + seg], H);  // hits_raw == hits
    }
}

extern "C" void kernel_launch(void* const* d_in, const int* in_sizes, int n_in,
                              void* d_out, int out_size, void* d_ws, size_t ws_size,
                              hipStream_t stream) {
    const float4* pred4   = (const float4*)d_in[0];
    const float4* obs4    = (const float4*)d_in[1];
    const float*  h_arr   = (const float*)d_in[2];
    const float*  lam_arr = (const float*)d_in[3];
    const float*  th_arr  = (const float*)d_in[4];
    float* out = (float*)d_out;

    // Harness poisons d_out to 0xAA before timed replays — zero it ourselves.
    hipMemsetAsync(out, 0, out_size * sizeof(float), stream);

    dim3 grid(ELT_BATCH * BLOCKS_PER_SEG);
    dim3 block(BLOCK);
    TrajectoryScore_58145267253396_kernel<<<grid, block, 0, stream>>>(
        pred4, obs4, h_arr, lam_arr, th_arr, out);
}

// Round 2
// 179.138 us; speedup vs baseline: 1.0016x; 1.0016x over previous
//
#include <hip/hip_runtime.h>

// TrajectoryScore: truncated-exponential mixture scoring + segment sums.
// 64 segments x 100,000 obs. 153.6 MB read-only stream.
//
// v3: software-pipelined, branch-free main loop. R1 showed coalescing alone is
// a null result (line traffic unchanged) and VGPR=28 proved the compiler sank
// the "batched" loads back into the consume loop (the act[u] guards gave it
// license). v3 removes all control flow from the body, prefetches iteration
// i+1's 4 float4 before computing iteration i, and pins the issue order with
// sched_barrier(0). Per-wave memory-in-flight duty -> ~100%.
// Chunk layout unchanged from v2 (63 f4 = 84 obs per wave-chunk, one
// __shfl_down repairs the 3-float obs straddle); per-thread accumulation order
// is bit-identical to v2.

constexpr int ELT_BATCH       = 64;
constexpr int OBS_PER_ELT     = 100000;
constexpr int F4_PER_SEG      = OBS_PER_ELT * 3 / 4;   // 75000 float4 per segment per array
constexpr int CHUNK_F4        = 63;                    // 63 f4 = 252 floats = 84 obs per wave-chunk
constexpr int CHUNKS_PER_SEG  = (F4_PER_SEG + CHUNK_F4 - 1) / CHUNK_F4;  // 1191
constexpr int BLOCKS_PER_SEG  = 32;
constexpr int BLOCK           = 256;
constexpr int WAVES_PER_BLOCK = BLOCK / 64;            // 4
constexpr int WAVES_PER_SEG   = BLOCKS_PER_SEG * WAVES_PER_BLOCK;  // 128
constexpr int PAIR_STRIDE     = 2 * WAVES_PER_SEG;     // 256 chunks consumed per iteration across the seg
constexpr int ITERS           = 5;                     // wseg + 4*256 + 128 = wseg+1152 >= chunk 1190 for all wseg

__device__ __forceinline__ float wave_reduce_sum(float v) {
    #pragma unroll
    for (int off = 32; off > 0; off >>= 1)
        v += __shfl_down(v, off, 64);
    return v;
}

__device__ __forceinline__ void eval_chunk(
    const float4 a, const float4 b, const int act,
    const int lane, const bool m0, const bool m1,
    const float nli, const float coef, const float omh, const float th,
    float& ll, float& hs)
{
    const float d0 = a.x - b.x, d1 = a.y - b.y, d2 = a.z - b.z, d3 = a.w - b.w;
    const float q0 = d0 * d0, q1 = d1 * d1, q2 = d2 * d2, q3 = d3 * d3;

    // "head" = leading components belonging to the obs straddling from lane-1.
    const float head = m1 ? (q0 + q1) : q0;
    const float hn   = __shfl_down(head, 1, 64);

    // obs A per lane: m0 -> obs 4g = q0+q1+q2 ; m1 -> obs 4g+2 = q2+q3+hn ;
    //                 m2 -> obs 4g+3 = q1+q2+q3.  obs B (m0 only): 4g+1 = q3+hn.
    const float t12 = q1 + q2;
    const float s2A = m0 ? (q0 + t12) : (m1 ? (q2 + q3 + hn) : (t12 + q3));
    const float s2B = q3 + hn;

    const bool lv = lane < act;   // act <= 0 disables all lanes (tail / overshoot)
    {
        const float e  = __expf(nli * s2A);
        const float ph = coef * e;
        const float p  = ph + omh;
        const float lp = __logf(p);
        const float po = ph / p;
        const bool  cl = (s2A < th) && lv;
        ll += cl ? lp : 0.0f;
        hs += (cl && po > 0.95f) ? po : 0.0f;
    }
    {
        const float e  = __expf(nli * s2B);
        const float ph = coef * e;
        const float p  = ph + omh;
        const float lp = __logf(p);
        const float po = ph / p;
        const bool  cl = (s2B < th) && lv && m0;
        ll += cl ? lp : 0.0f;
        hs += (cl && po > 0.95f) ? po : 0.0f;
    }
}

__global__ __launch_bounds__(BLOCK, 8) void TrajectoryScore_58145267253396_kernel(
    const float4* __restrict__ pred4,
    const float4* __restrict__ obs4,
    const float*  __restrict__ h_arr,
    const float*  __restrict__ lam_arr,
    const float*  __restrict__ th_arr,
    float*        __restrict__ out)
{
    const int seg        = blockIdx.x / BLOCKS_PER_SEG;
    const int blk_in_seg = blockIdx.x % BLOCKS_PER_SEG;
    const int tid  = threadIdx.x;
    const int lane = tid & 63;
    const int wave = tid >> 6;
    const int wseg = blk_in_seg * WAVES_PER_BLOCK + wave;   // 0..127 within segment

    // Wave-uniform per-segment params (broadcast scalar loads).
    const float h      = h_arr[seg];
    const float lam    = lam_arr[seg];
    const float th     = th_arr[seg];
    const float inv_th = 1.0f / th;
    const float coef   = h * lam / (1.0f - __expf(-lam));
    const float omh    = 1.0f - h;
    const float nli    = -lam * inv_th;

    const int  m  = lane % 3;
    const bool m0 = (m == 0);
    const bool m1 = (m == 1);

    const int seg_f4 = seg * F4_PER_SEG;

    float ll = 0.0f;
    float hs = 0.0f;

    // Clamped coalesced loader: lane i -> f4[c*63 + i]; overshooting chunks
    // re-read the last valid f4 of the segment (harmless, masked by act).
    auto ld = [&](int c, float4& A, float4& B) {
        const int idx = seg_f4 + min(c * CHUNK_F4 + lane, F4_PER_SEG - 1);
        A = pred4[idx];
        B = obs4[idx];
    };

    // ---- software pipeline: prefetch (it+1) while computing (it) ----
    float4 A0, B0, A1, B1, A0n, B0n, A1n, B1n;
    ld(wseg,                   A0, B0);
    ld(wseg + WAVES_PER_SEG,   A1, B1);

    #pragma unroll
    for (int it = 0; it < ITERS; ++it) {
        const int cn = wseg + (it + 1) * PAIR_STRIDE;
        ld(cn,                 A0n, B0n);
        ld(cn + WAVES_PER_SEG, A1n, B1n);
        // Pin the prefetch issue above the compute so the scheduler cannot
        // sink the loads back to their uses (R1 failure mode, VGPR=28).
        __builtin_amdgcn_sched_barrier(0);

        const int c = wseg + it * PAIR_STRIDE;
        eval_chunk(A0, B0, F4_PER_SEG - c * CHUNK_F4 < CHUNK_F4 ? F4_PER_SEG - c * CHUNK_F4 : CHUNK_F4,
                   lane, m0, m1, nli, coef, omh, th, ll, hs);
        eval_chunk(A1, B1, F4_PER_SEG - (c + WAVES_PER_SEG) * CHUNK_F4 < CHUNK_F4
                              ? F4_PER_SEG - (c + WAVES_PER_SEG) * CHUNK_F4 : CHUNK_F4,
                   lane, m0, m1, nli, coef, omh, th, ll, hs);

        A0 = A0n; B0 = B0n; A1 = A1n; B1 = B1n;
    }

    // Block reduction: 64-lane shuffle, then LDS across the 4 waves.
    ll = wave_reduce_sum(ll);
    hs = wave_reduce_sum(hs);

    __shared__ float sll[WAVES_PER_BLOCK];
    __shared__ float shs[WAVES_PER_BLOCK];
    if (lane == 0) { sll[wave] = ll; shs[wave] = hs; }
    __syncthreads();
    if (tid == 0) {
        float L = 0.0f, H = 0.0f;
        #pragma unroll
        for (int w = 0; w < WAVES_PER_BLOCK; ++w) { L += sll[w]; H += shs[w]; }
        atomicAdd(&out[seg], L);
        atomicAdd(&out[ELT_BATCH + seg], H);
        atomicAdd(&out[2 * ELT_BATCH + seg], H);  // hits_raw == hits
    }
}

extern "C" void kernel_launch(void* const* d_in, const int* in_sizes, int n_in,
                              void* d_out, int out_size, void* d_ws, size_t ws_size,
                              hipStream_t stream) {
    const float4* pred4   = (const float4*)d_in[0];
    const float4* obs4    = (const float4*)d_in[1];
    const float*  h_arr   = (const float*)d_in[2];
    const float*  lam_arr = (const float*)d_in[3];
    const float*  th_arr  = (const float*)d_in[4];
    float* out = (float*)d_out;

    // Harness poisons d_out to 0xAA before timed replays — zero it ourselves.
    hipMemsetAsync(out, 0, out_size * sizeof(float), stream);

    dim3 grid(ELT_BATCH * BLOCKS_PER_SEG);
    dim3 block(BLOCK);
    TrajectoryScore_58145267253396_kernel<<<grid, block, 0, stream>>>(
        pred4, obs4, h_arr, lam_arr, th_arr, out);
}